// Round 1
// baseline (1870.854 us; speedup 1.0000x reference)
//
#include <hip/hip_runtime.h>
#include <math.h>

#define NN 50000
#define NE 1600000

static inline int cdiv(int a, int b){ return (a + b - 1) / b; }

// ---------------- graph normalization ----------------

__global__ void k_init_deg(float* __restrict__ deg, int n){
  int i = blockIdx.x*256 + threadIdx.x;
  if (i < n) deg[i] = 1.0f;                      // self-loop weight
}

__global__ void k_deg_edges(const int* __restrict__ dst, const float* __restrict__ ew,
                            float* __restrict__ deg, int e){
  int i = blockIdx.x*256 + threadIdx.x;
  if (i < e) atomicAdd(&deg[dst[i]], ew[i]);
}

__global__ void k_dinv(float* __restrict__ deg, int n){
  int i = blockIdx.x*256 + threadIdx.x;
  if (i < n){ float d = deg[i]; deg[i] = (d > 0.f) ? rsqrtf(d) : 0.f; }
}

__global__ void k_norm(const int* __restrict__ src, const int* __restrict__ dst,
                       const float* __restrict__ ew, const float* __restrict__ dinv,
                       float* __restrict__ nrm, int e){
  int i = blockIdx.x*256 + threadIdx.x;
  if (i < e) nrm[i] = dinv[src[i]] * ew[i] * dinv[dst[i]];
}

// ---------------- dense transforms ----------------

// out[n,64] = act(in[n,FIN]) @ W[FIN,64]; lanes 0..63 of a wave share a node.
template<int FIN, bool RELU>
__global__ void k_xform64(const float* __restrict__ in, const float* __restrict__ W,
                          float* __restrict__ out, int n){
  __shared__ float Ws[FIN*64];
  for (int t = threadIdx.x; t < FIN*64; t += 256) Ws[t] = W[t];
  __syncthreads();
  int tid = blockIdx.x*256 + threadIdx.x;
  int node = tid >> 6, j = tid & 63;
  if (node >= n) return;
  const float* row = in + (size_t)node*FIN;
  float acc = 0.f;
  #pragma unroll
  for (int k = 0; k < FIN; ++k){
    float v = row[k];
    if (RELU) v = fmaxf(v, 0.f);
    acc = fmaf(v, Ws[k*64 + j], acc);
  }
  out[(size_t)node*64 + j] = acc;
}

// out[n] = act(in[n,64]) @ W[64,1]
template<bool RELU>
__global__ void k_xform1(const float* __restrict__ in, const float* __restrict__ W,
                         float* __restrict__ out, int n){
  __shared__ float Ws[64];
  if (threadIdx.x < 64) Ws[threadIdx.x] = W[threadIdx.x];
  __syncthreads();
  int i = blockIdx.x*256 + threadIdx.x;
  if (i >= n) return;
  const float4* row = (const float4*)(in + (size_t)i*64);
  float acc = 0.f;
  #pragma unroll
  for (int k = 0; k < 16; ++k){
    float4 v = row[k];
    if (RELU){ v.x=fmaxf(v.x,0.f); v.y=fmaxf(v.y,0.f); v.z=fmaxf(v.z,0.f); v.w=fmaxf(v.w,0.f); }
    acc = fmaf(v.x, Ws[4*k+0], acc);
    acc = fmaf(v.y, Ws[4*k+1], acc);
    acc = fmaf(v.z, Ws[4*k+2], acc);
    acc = fmaf(v.w, Ws[4*k+3], acc);
  }
  out[i] = acc;
}

// ---------------- aggregation (self-loop init + edge scatter) ----------------

__global__ void k_init64(const float* __restrict__ xw, const float* __restrict__ dinv,
                         const float* __restrict__ b, float* __restrict__ out, int n){
  int tid = blockIdx.x*256 + threadIdx.x;
  int node = tid >> 6, j = tid & 63;
  if (node >= n) return;
  float di = dinv[node];
  out[tid] = xw[tid]*(di*di) + b[j];
}

__global__ void k_agg64(const int* __restrict__ src, const int* __restrict__ dst,
                        const float* __restrict__ nrm, const float* __restrict__ xw,
                        float* __restrict__ out, int e){
  int tid = blockIdx.x*256 + threadIdx.x;   // E*64 = 102.4M < 2^31
  int ei = tid >> 6, f = tid & 63;
  if (ei >= e) return;
  int s = src[ei], d = dst[ei];             // wave-uniform broadcast loads
  float w = nrm[ei];
  atomicAdd(&out[(size_t)d*64 + f], w * xw[(size_t)s*64 + f]);
}

__global__ void k_init1(const float* __restrict__ xw, const float* __restrict__ dinv,
                        const float* __restrict__ b, float* __restrict__ out, int n){
  int i = blockIdx.x*256 + threadIdx.x;
  if (i >= n) return;
  float di = dinv[i];
  out[i] = xw[i]*(di*di) + b[0];
}

__global__ void k_agg1(const int* __restrict__ src, const int* __restrict__ dst,
                       const float* __restrict__ nrm, const float* __restrict__ xw,
                       float* __restrict__ out, int e){
  int i = blockIdx.x*256 + threadIdx.x;
  if (i >= e) return;
  atomicAdd(&out[dst[i]], nrm[i] * xw[src[i]]);
}

// ---------------- epilogues ----------------

// xsol = h*Wl + bl ; xin = cat(x, xsol)
__global__ void k_xsol_xin(const float* __restrict__ h, const float* __restrict__ Wl,
                           const float* __restrict__ bl, const float* __restrict__ x,
                           float* __restrict__ xsol, float* __restrict__ xin, int n){
  int i = blockIdx.x*256 + threadIdx.x;
  if (i >= n) return;
  float v = h[i]*Wl[0] + bl[0];
  xsol[i] = v;
  xin[i*5+0] = x[i*4+0];
  xin[i*5+1] = x[i*4+1];
  xin[i*5+2] = x[i*4+2];
  xin[i*5+3] = x[i*4+3];
  xin[i*5+4] = v;
}

__global__ void k_final(const float* __restrict__ h, const float* __restrict__ Wl,
                        const float* __restrict__ bl, const float* __restrict__ xsol,
                        const float* __restrict__ x, float* __restrict__ out, int n){
  int i = blockIdx.x*256 + threadIdx.x;
  if (i >= n) return;
  float g = h[i]*Wl[0] + bl[0];
  float gamma = 1.f / (1.f + expf(-g));
  float xl = x[i*4+3];
  out[i]     = xl + gamma*(xsol[i] - xl);
  out[n + i] = gamma;
}

// ---------------- launch ----------------

extern "C" void kernel_launch(void* const* d_in, const int* in_sizes, int n_in,
                              void* d_out, int out_size, void* d_ws, size_t ws_size,
                              hipStream_t stream){
  const float* x   = (const float*)d_in[0];
  const int*   ei  = (const int*)d_in[1];
  const float* ew  = (const float*)d_in[2];
  const float* oW0 = (const float*)d_in[3];
  const float* ob0 = (const float*)d_in[4];
  const float* oW1 = (const float*)d_in[5];
  const float* ob1 = (const float*)d_in[6];
  const float* oW2 = (const float*)d_in[7];
  const float* ob2 = (const float*)d_in[8];
  const float* oWl = (const float*)d_in[9];
  const float* obl = (const float*)d_in[10];
  const float* gW0 = (const float*)d_in[11];
  const float* gb0 = (const float*)d_in[12];
  const float* gW1 = (const float*)d_in[13];
  const float* gb1 = (const float*)d_in[14];
  const float* gW2 = (const float*)d_in[15];
  const float* gb2 = (const float*)d_in[16];
  const float* gWl = (const float*)d_in[17];
  const float* gbl = (const float*)d_in[18];

  const int n = NN, e = NE;
  const int* src = ei;
  const int* dst = ei + e;

  float* ws   = (float*)d_ws;
  float* dinv = ws;  ws += n;
  float* nrm  = ws;  ws += e;
  float* bufA = ws;  ws += (size_t)n*64;
  float* bufB = ws;  ws += (size_t)n*64;
  float* s0   = ws;  ws += n;
  float* s1   = ws;  ws += n;
  float* xsol = ws;  ws += n;
  float* xin  = ws;  ws += (size_t)n*5;

  dim3 b256(256);
  int gn   = cdiv(n, 256);
  int ge   = cdiv(e, 256);
  int gn64 = cdiv(n*64, 256);
  int ge64 = (int)(((long long)e*64 + 255) / 256);

  // shared normalization (identical for all 6 convs)
  k_init_deg <<<gn, b256, 0, stream>>>(dinv, n);
  k_deg_edges<<<ge, b256, 0, stream>>>(dst, ew, dinv, e);
  k_dinv     <<<gn, b256, 0, stream>>>(dinv, n);
  k_norm     <<<ge, b256, 0, stream>>>(src, dst, ew, dinv, nrm, e);

  // ---- optim tower: 4 -> 64 -> 64 -> 1, Linear(1,1) ----
  k_xform64<4,false><<<gn64, b256, 0, stream>>>(x, oW0, bufA, n);
  k_init64 <<<gn64, b256, 0, stream>>>(bufA, dinv, ob0, bufB, n);
  k_agg64  <<<ge64, b256, 0, stream>>>(src, dst, nrm, bufA, bufB, e);
  k_xform64<64,true><<<gn64, b256, 0, stream>>>(bufB, oW1, bufA, n);
  k_init64 <<<gn64, b256, 0, stream>>>(bufA, dinv, ob1, bufB, n);
  k_agg64  <<<ge64, b256, 0, stream>>>(src, dst, nrm, bufA, bufB, e);
  k_xform1<true><<<gn, b256, 0, stream>>>(bufB, oW2, s0, n);
  k_init1  <<<gn, b256, 0, stream>>>(s0, dinv, ob2, s1, n);
  k_agg1   <<<ge, b256, 0, stream>>>(src, dst, nrm, s0, s1, e);
  k_xsol_xin<<<gn, b256, 0, stream>>>(s1, oWl, obl, x, xsol, xin, n);

  // ---- gamma tower: 5 -> 64 -> 64 -> 1, Linear(1,1), sigmoid ----
  k_xform64<5,false><<<gn64, b256, 0, stream>>>(xin, gW0, bufA, n);
  k_init64 <<<gn64, b256, 0, stream>>>(bufA, dinv, gb0, bufB, n);
  k_agg64  <<<ge64, b256, 0, stream>>>(src, dst, nrm, bufA, bufB, e);
  k_xform64<64,true><<<gn64, b256, 0, stream>>>(bufB, gW1, bufA, n);
  k_init64 <<<gn64, b256, 0, stream>>>(bufA, dinv, gb1, bufB, n);
  k_agg64  <<<ge64, b256, 0, stream>>>(src, dst, nrm, bufA, bufB, e);
  k_xform1<true><<<gn, b256, 0, stream>>>(bufB, gW2, s0, n);
  k_init1  <<<gn, b256, 0, stream>>>(s0, dinv, gb2, s1, n);
  k_agg1   <<<ge, b256, 0, stream>>>(src, dst, nrm, s0, s1, e);
  k_final  <<<gn, b256, 0, stream>>>(s1, gWl, gbl, xsol, x, (float*)d_out, n);
}

// Round 2
// 738.159 us; speedup vs baseline: 2.5345x; 2.5345x over previous
//
#include <hip/hip_runtime.h>
#include <math.h>

#define NN 50000
#define NE 1600000

static inline int cdiv(int a, int b){ return (a + b - 1) / b; }

// ---------------- CSR build (counting sort by dst) ----------------

__global__ void k_zero_i(int* __restrict__ p, int n){
  int i = blockIdx.x*256 + threadIdx.x;
  if (i < n) p[i] = 0;
}

__global__ void k_hist(const int* __restrict__ dst, int* __restrict__ cnt, int e){
  int i = blockIdx.x*256 + threadIdx.x;
  if (i < e) atomicAdd(&cnt[dst[i]], 1);
}

__global__ void k_blocksum(const int* __restrict__ cnt, int* __restrict__ bsum, int n){
  __shared__ int sh[256];
  int t = threadIdx.x, i = blockIdx.x*256 + t;
  sh[t] = (i < n) ? cnt[i] : 0;
  __syncthreads();
  for (int o = 128; o > 0; o >>= 1){
    if (t < o) sh[t] += sh[t+o];
    __syncthreads();
  }
  if (t == 0) bsum[blockIdx.x] = sh[0];
}

__global__ void k_scan_bsum(const int* __restrict__ bsum, int* __restrict__ boff, int nb){
  __shared__ int sh[256];
  int t = threadIdx.x;
  int v = (t < nb) ? bsum[t] : 0;
  sh[t] = v; __syncthreads();
  for (int o = 1; o < 256; o <<= 1){
    int u = (t >= o) ? sh[t-o] : 0;
    __syncthreads();
    sh[t] += u;
    __syncthreads();
  }
  boff[t] = sh[t] - v;   // exclusive
}

__global__ void k_scan_final(const int* __restrict__ cnt, const int* __restrict__ boff,
                             int* __restrict__ row, int* __restrict__ cur, int n){
  __shared__ int sh[256];
  int t = threadIdx.x, i = blockIdx.x*256 + t;
  int v = (i < n) ? cnt[i] : 0;
  sh[t] = v; __syncthreads();
  for (int o = 1; o < 256; o <<= 1){
    int u = (t >= o) ? sh[t-o] : 0;
    __syncthreads();
    sh[t] += u;
    __syncthreads();
  }
  if (i < n){
    int val = sh[t] - v + boff[blockIdx.x];
    row[i] = val;
    cur[i] = val;
    if (i == n-1) row[n] = val + v;
  }
}

__global__ void k_scatter(const int* __restrict__ src, const int* __restrict__ dst,
                          const float* __restrict__ ew, int* __restrict__ cur,
                          int2* __restrict__ packed, int e){
  int i = blockIdx.x*256 + threadIdx.x;
  if (i >= e) return;
  int pos = atomicAdd(&cur[dst[i]], 1);
  packed[pos] = make_int2(src[i], __float_as_int(ew[i]));
}

// one wave per node: deg = 1 + sum(ew over in-edges); dinv = rsqrt(deg)
__global__ void k_deg_dinv(const int* __restrict__ row, const int2* __restrict__ packed,
                           float* __restrict__ dinv, int n){
  int tid = blockIdx.x*256 + threadIdx.x;
  int node = tid >> 6, lane = tid & 63;
  if (node >= n) return;
  int beg = row[node], end = row[node+1];
  float s = 0.f;
  for (int p = beg + lane; p < end; p += 64) s += __int_as_float(packed[p].y);
  for (int o = 32; o > 0; o >>= 1) s += __shfl_down(s, o, 64);
  if (lane == 0) dinv[node] = rsqrtf(1.f + s);   // deg >= 1 always (self-loop)
}

// one wave per node: w_slot = ew * dinv[src] * dinv[node] (in place)
__global__ void k_nrm(const int* __restrict__ row, int2* __restrict__ packed,
                      const float* __restrict__ dinv, int n){
  int tid = blockIdx.x*256 + threadIdx.x;
  int node = tid >> 6, lane = tid & 63;
  if (node >= n) return;
  float di = dinv[node];
  int beg = row[node], end = row[node+1];
  for (int p = beg + lane; p < end; p += 64){
    int2 ed = packed[p];
    float w = __int_as_float(ed.y) * di * dinv[ed.x];
    ((float*)packed)[2*p + 1] = w;
  }
}

// ---------------- dense transforms ----------------

template<int FIN, bool RELU>
__global__ void k_xform64(const float* __restrict__ in, const float* __restrict__ W,
                          float* __restrict__ out, int n){
  __shared__ float Ws[FIN*64];
  for (int t = threadIdx.x; t < FIN*64; t += 256) Ws[t] = W[t];
  __syncthreads();
  int tid = blockIdx.x*256 + threadIdx.x;
  int node = tid >> 6, j = tid & 63;
  if (node >= n) return;
  const float* rowp = in + (size_t)node*FIN;
  float acc = 0.f;
  #pragma unroll
  for (int k = 0; k < FIN; ++k){
    float v = rowp[k];
    if (RELU) v = fmaxf(v, 0.f);
    acc = fmaf(v, Ws[k*64 + j], acc);
  }
  out[tid] = acc;
}

template<bool RELU>
__global__ void k_xform1(const float* __restrict__ in, const float* __restrict__ W,
                         float* __restrict__ out, int n){
  __shared__ float Ws[64];
  if (threadIdx.x < 64) Ws[threadIdx.x] = W[threadIdx.x];
  __syncthreads();
  int i = blockIdx.x*256 + threadIdx.x;
  if (i >= n) return;
  const float4* rowp = (const float4*)(in + (size_t)i*64);
  float acc = 0.f;
  #pragma unroll
  for (int k = 0; k < 16; ++k){
    float4 v = rowp[k];
    if (RELU){ v.x=fmaxf(v.x,0.f); v.y=fmaxf(v.y,0.f); v.z=fmaxf(v.z,0.f); v.w=fmaxf(v.w,0.f); }
    acc = fmaf(v.x, Ws[4*k+0], acc);
    acc = fmaf(v.y, Ws[4*k+1], acc);
    acc = fmaf(v.z, Ws[4*k+2], acc);
    acc = fmaf(v.w, Ws[4*k+3], acc);
  }
  out[i] = acc;
}

// ---------------- CSR aggregation (no atomics) ----------------

// one wave per dst node; lanes = 64 features; self-loop + bias fused
__global__ void k_agg64_csr(const int* __restrict__ row, const int2* __restrict__ packed,
                            const float* __restrict__ xw, const float* __restrict__ dinv,
                            const float* __restrict__ b, float* __restrict__ out, int n){
  int tid = blockIdx.x*256 + threadIdx.x;
  int node = tid >> 6, j = tid & 63;
  if (node >= n) return;
  float di = dinv[node];
  float acc = xw[tid]*(di*di) + b[j];
  int p = row[node], end = row[node+1];
  for (; p + 4 <= end; p += 4){
    int2 e0 = packed[p], e1 = packed[p+1], e2 = packed[p+2], e3 = packed[p+3];
    float x0 = xw[e0.x*64 + j];
    float x1 = xw[e1.x*64 + j];
    float x2 = xw[e2.x*64 + j];
    float x3 = xw[e3.x*64 + j];
    acc = fmaf(__int_as_float(e0.y), x0, acc);
    acc = fmaf(__int_as_float(e1.y), x1, acc);
    acc = fmaf(__int_as_float(e2.y), x2, acc);
    acc = fmaf(__int_as_float(e3.y), x3, acc);
  }
  for (; p < end; ++p){
    int2 ed = packed[p];
    acc = fmaf(__int_as_float(ed.y), xw[ed.x*64 + j], acc);
  }
  out[tid] = acc;
}

// scalar agg + Linear(1,1) + build xin = cat(x, xsol)
__global__ void k_agg1_xsol(const int* __restrict__ row, const int2* __restrict__ packed,
                            const float* __restrict__ s0, const float* __restrict__ dinv,
                            const float* __restrict__ b, const float* __restrict__ Wl,
                            const float* __restrict__ bl, const float* __restrict__ x,
                            float* __restrict__ xsol, float* __restrict__ xin, int n){
  int i = blockIdx.x*256 + threadIdx.x;
  if (i >= n) return;
  float di = dinv[i];
  float acc = s0[i]*(di*di) + b[0];
  int end = row[i+1];
  for (int p = row[i]; p < end; ++p){
    int2 ed = packed[p];
    acc = fmaf(__int_as_float(ed.y), s0[ed.x], acc);
  }
  float v = acc*Wl[0] + bl[0];
  xsol[i] = v;
  float4 xv = ((const float4*)x)[i];
  xin[i*5+0] = xv.x;
  xin[i*5+1] = xv.y;
  xin[i*5+2] = xv.z;
  xin[i*5+3] = xv.w;
  xin[i*5+4] = v;
}

// scalar agg + Linear(1,1) + sigmoid + gated residual combine
__global__ void k_agg1_final(const int* __restrict__ row, const int2* __restrict__ packed,
                             const float* __restrict__ s0, const float* __restrict__ dinv,
                             const float* __restrict__ b, const float* __restrict__ Wl,
                             const float* __restrict__ bl, const float* __restrict__ xsol,
                             const float* __restrict__ x, float* __restrict__ out, int n){
  int i = blockIdx.x*256 + threadIdx.x;
  if (i >= n) return;
  float di = dinv[i];
  float acc = s0[i]*(di*di) + b[0];
  int end = row[i+1];
  for (int p = row[i]; p < end; ++p){
    int2 ed = packed[p];
    acc = fmaf(__int_as_float(ed.y), s0[ed.x], acc);
  }
  float g = acc*Wl[0] + bl[0];
  float gamma = 1.f / (1.f + expf(-g));
  float xl = x[i*4+3];
  out[i]     = xl + gamma*(xsol[i] - xl);
  out[n + i] = gamma;
}

// ---------------- launch ----------------

extern "C" void kernel_launch(void* const* d_in, const int* in_sizes, int n_in,
                              void* d_out, int out_size, void* d_ws, size_t ws_size,
                              hipStream_t stream){
  const float* x   = (const float*)d_in[0];
  const int*   ei  = (const int*)d_in[1];
  const float* ew  = (const float*)d_in[2];
  const float* oW0 = (const float*)d_in[3];
  const float* ob0 = (const float*)d_in[4];
  const float* oW1 = (const float*)d_in[5];
  const float* ob1 = (const float*)d_in[6];
  const float* oW2 = (const float*)d_in[7];
  const float* ob2 = (const float*)d_in[8];
  const float* oWl = (const float*)d_in[9];
  const float* obl = (const float*)d_in[10];
  const float* gW0 = (const float*)d_in[11];
  const float* gb0 = (const float*)d_in[12];
  const float* gW1 = (const float*)d_in[13];
  const float* gb1 = (const float*)d_in[14];
  const float* gW2 = (const float*)d_in[15];
  const float* gb2 = (const float*)d_in[16];
  const float* gWl = (const float*)d_in[17];
  const float* gbl = (const float*)d_in[18];

  const int n = NN, e = NE;
  const int* src = ei;
  const int* dst = ei + e;

  // workspace layout (packed first for 8B alignment)
  char* wsb = (char*)d_ws;
  int2*  packed = (int2*)wsb;                 wsb += (size_t)e*sizeof(int2);
  int*   cnt    = (int*)wsb;                  wsb += (size_t)n*4;
  int*   cur    = (int*)wsb;                  wsb += (size_t)n*4;
  int*   row    = (int*)wsb;                  wsb += (size_t)(n+1)*4;
  int*   bsum   = (int*)wsb;                  wsb += 256*4;
  int*   boff   = (int*)wsb;                  wsb += 256*4;
  float* dinv   = (float*)wsb;                wsb += (size_t)n*4;
  float* bufA   = (float*)wsb;                wsb += (size_t)n*64*4;
  float* bufB   = (float*)wsb;                wsb += (size_t)n*64*4;
  float* s0     = (float*)wsb;                wsb += (size_t)n*4;
  float* xsol   = (float*)wsb;                wsb += (size_t)n*4;
  float* xin    = (float*)wsb;                wsb += (size_t)n*5*4;

  dim3 b256(256);
  int gn   = cdiv(n, 256);        // 196
  int ge   = cdiv(e, 256);        // 6250
  int gw   = cdiv(n*64, 256);     // 12500 (wave-per-node kernels)

  // ---- CSR build + normalization (shared by all 6 convs) ----
  k_zero_i    <<<gn, b256, 0, stream>>>(cnt, n);
  k_hist      <<<ge, b256, 0, stream>>>(dst, cnt, e);
  k_blocksum  <<<gn, b256, 0, stream>>>(cnt, bsum, n);
  k_scan_bsum <<<1,  b256, 0, stream>>>(bsum, boff, gn);
  k_scan_final<<<gn, b256, 0, stream>>>(cnt, boff, row, cur, n);
  k_scatter   <<<ge, b256, 0, stream>>>(src, dst, ew, cur, packed, e);
  k_deg_dinv  <<<gw, b256, 0, stream>>>(row, packed, dinv, n);
  k_nrm       <<<gw, b256, 0, stream>>>(row, packed, dinv, n);

  // ---- optim tower: 4 -> 64 -> 64 -> 1, Linear(1,1) ----
  k_xform64<4,false><<<gw, b256, 0, stream>>>(x, oW0, bufA, n);
  k_agg64_csr       <<<gw, b256, 0, stream>>>(row, packed, bufA, dinv, ob0, bufB, n);
  k_xform64<64,true><<<gw, b256, 0, stream>>>(bufB, oW1, bufA, n);
  k_agg64_csr       <<<gw, b256, 0, stream>>>(row, packed, bufA, dinv, ob1, bufB, n);
  k_xform1<true>    <<<gn, b256, 0, stream>>>(bufB, oW2, s0, n);
  k_agg1_xsol       <<<gn, b256, 0, stream>>>(row, packed, s0, dinv, ob2, oWl, obl, x, xsol, xin, n);

  // ---- gamma tower: 5 -> 64 -> 64 -> 1, Linear(1,1), sigmoid ----
  k_xform64<5,false><<<gw, b256, 0, stream>>>(xin, gW0, bufA, n);
  k_agg64_csr       <<<gw, b256, 0, stream>>>(row, packed, bufA, dinv, gb0, bufB, n);
  k_xform64<64,true><<<gw, b256, 0, stream>>>(bufB, gW1, bufA, n);
  k_agg64_csr       <<<gw, b256, 0, stream>>>(row, packed, bufA, dinv, gb1, bufB, n);
  k_xform1<true>    <<<gn, b256, 0, stream>>>(bufB, gW2, s0, n);
  k_agg1_final      <<<gn, b256, 0, stream>>>(row, packed, s0, dinv, gb2, gWl, gbl, xsol, x, (float*)d_out, n);
}